// Round 7
// baseline (301.975 us; speedup 1.0000x reference)
//
#include <hip/hip_runtime.h>
#include <hip/hip_bf16.h>

#define Bb 64
#define Ll 200
#define NSs 1000
#define Dd 128
#define Mm 50

__device__ __forceinline__ float bcast_lane(float v, int l) {
    return __int_as_float(__builtin_amdgcn_readlane(__float_as_int(v), l));
}

// ============ kernel 1: w = softmax(k @ Mk^T) over M=50 ============
// 256 thr = 4 waves, 8 pos/wave. Lane (<50) holds its Mk row in 32 float4 VGPRs;
// k-row values come in via scalar loads (wave-uniform address). No LDS.
__global__ void __launch_bounds__(256) kern_w(
        const int* __restrict__ skills,
        const float* __restrict__ k_emb,
        const float* __restrict__ Mk,
        float* __restrict__ w_out) {
    int tid = threadIdx.x, blk = blockIdx.x;
    int wave = tid >> 6, lane = tid & 63;
    int mrow = (lane < Mm) ? lane : (Mm - 1);
    const float4* wp = (const float4*)(Mk + (size_t)mrow * Dd);
    float4 wreg[32];
#pragma unroll
    for (int j = 0; j < 32; ++j) wreg[j] = wp[j];

    for (int p = 0; p < 8; ++p) {
        int bl = blk * 32 + wave * 8 + p;
        int sk = __builtin_amdgcn_readfirstlane(skills[bl]);
        const float4* kp = (const float4*)(k_emb + (size_t)sk * Dd);
        float acc = 0.f;
#pragma unroll
        for (int j = 0; j < 32; ++j) {
            float4 kv = kp[j];                     // uniform -> s_load
            acc = fmaf(wreg[j].x, kv.x, acc);
            acc = fmaf(wreg[j].y, kv.y, acc);
            acc = fmaf(wreg[j].z, kv.z, acc);
            acc = fmaf(wreg[j].w, kv.w, acc);
        }
        float logit = (lane < Mm) ? acc : -1e30f;
        float mx = logit;
        for (int off = 32; off > 0; off >>= 1) mx = fmaxf(mx, __shfl_down(mx, off));
        mx = __shfl(mx, 0);
        float ex = (lane < Mm) ? expf(logit - mx) : 0.f;
        float sm = ex;
        for (int off = 32; off > 0; off >>= 1) sm += __shfl_down(sm, off);
        sm = __shfl(sm, 0);
        if (lane < Mm) w_out[(size_t)bl * Mm + lane] = ex / sm;
    }
}

// ============ kernel 2: e = sigmoid(V@eW^T+eb), a = tanh(V@aW^T+ab) ============
// 256 thr = 4 waves: wave0/1 -> e rows 0-63/64-127, wave2/3 -> a rows.
// Lane holds its weight row in VGPRs; v-row via scalar loads. No LDS. 32 pos/block.
__global__ void __launch_bounds__(256) kern_ea(
        const int* __restrict__ skills,
        const int* __restrict__ responses,
        const float* __restrict__ v_emb,
        const float* __restrict__ e_W, const float* __restrict__ e_b,
        const float* __restrict__ a_W, const float* __restrict__ a_b,
        float* __restrict__ e_out, float* __restrict__ a_out) {
    int tid = threadIdx.x, blk = blockIdx.x;
    int wave = tid >> 6, lane = tid & 63;
    bool is_e = (wave < 2);
    int row = (wave & 1) * 64 + lane;                  // 0..127
    const float* W = is_e ? e_W : a_W;
    float bias = (is_e ? e_b : a_b)[row];
    float* dst = is_e ? e_out : a_out;
    const float4* wp = (const float4*)(W + (size_t)row * Dd);
    float4 wreg[32];
#pragma unroll
    for (int j = 0; j < 32; ++j) wreg[j] = wp[j];

    for (int p = 0; p < 32; ++p) {
        int bl = blk * 32 + p;
        int rr = responses[bl];
        int x  = skills[bl] + NSs * ((rr > -1) ? rr : 0);
        x = __builtin_amdgcn_readfirstlane(x);
        const float4* vp = (const float4*)(v_emb + (size_t)x * Dd);
        float acc = 0.f;
#pragma unroll
        for (int j = 0; j < 32; ++j) {
            float4 v = vp[j];                      // uniform -> s_load
            acc = fmaf(wreg[j].x, v.x, acc);
            acc = fmaf(wreg[j].y, v.y, acc);
            acc = fmaf(wreg[j].z, v.z, acc);
            acc = fmaf(wreg[j].w, v.w, acc);
        }
        acc += bias;
        float r = is_e ? (1.f / (1.f + expf(-acc))) : tanhf(acc);
        dst[(size_t)bl * Dd + row] = r;            // coalesced across lanes
    }
}

// ============ scan pass 1: per-chunk affine transfer (P, Q) ============
#define PQ_LOAD(S, tt) do { int _t = (tt);                                   \
    if (_t < T) { size_t _bl = blBase + _t;                                  \
        w##S = (lane < Mm) ? w_ws[_bl * Mm + lane] : 0.f;                    \
        e##S = e_ws[_bl * Dd + d];  a##S = a_ws[_bl * Dd + d]; } } while (0)

#define PQ_BODY(S) do {                                                      \
    _Pragma("unroll")                                                        \
    for (int m = 0; m < Mm; ++m) {                                           \
        float wm = bcast_lane(w##S, m);                                      \
        float A  = fmaf(-wm, e##S, 1.f);                                     \
        Q[m] = fmaf(A, Q[m], wm * a##S);                                     \
        P[m] *= A; } } while (0)

__global__ void __launch_bounds__(128) kern_scan_pq(
        const float* __restrict__ w_ws,
        const float* __restrict__ e_ws,
        const float* __restrict__ a_ws,
        float* __restrict__ P_ws, float* __restrict__ Q_ws,
        int C, int T) {
    int b = blockIdx.x / C, c = blockIdx.x % C;
    int d = threadIdx.x;
    int lane = d & 63;
    float P[Mm], Q[Mm];
#pragma unroll
    for (int m = 0; m < Mm; ++m) { P[m] = 1.f; Q[m] = 0.f; }

    size_t blBase = (size_t)b * Ll + (size_t)c * T;
    float w0 = 0.f, e0 = 0.f, a0 = 0.f;
    float w1 = 0.f, e1 = 0.f, a1 = 0.f;
    float w2 = 0.f, e2 = 0.f, a2 = 0.f;
    PQ_LOAD(0, 0);
    PQ_LOAD(1, 1);
    for (int tt = 0; tt < T; tt += 3) {
        PQ_LOAD(2, tt + 2);  PQ_BODY(0);
        if (tt + 1 < T) { PQ_LOAD(0, tt + 3);  PQ_BODY(1); }
        if (tt + 2 < T) { PQ_LOAD(1, tt + 4);  PQ_BODY(2); }
    }
    size_t base = ((size_t)(b * C + c)) * (Mm * Dd) + d;
#pragma unroll
    for (int m = 0; m < Mm; ++m) {
        P_ws[base + m * Dd] = P[m];
        Q_ws[base + m * Dd] = Q[m];
    }
}

// ============ scan pass 2: chunk-boundary combine (compile-time C) ============
template <int CC>
__global__ void kern_scan_comb_t(
        const float* __restrict__ Mv0,
        const float* __restrict__ P_ws, const float* __restrict__ Q_ws,
        float* __restrict__ S_ws) {
    int idx = blockIdx.x * 256 + threadIdx.x;
    int b   = idx / (Mm * Dd);
    int md  = idx % (Mm * Dd);
    float Pr[CC - 1], Qr[CC - 1];
#pragma unroll
    for (int c = 0; c < CC - 1; ++c) {
        size_t pq = ((size_t)(b * CC + c)) * (Mm * Dd) + md;
        Pr[c] = P_ws[pq];
        Qr[c] = Q_ws[pq];
    }
    float s = Mv0[md];
#pragma unroll
    for (int c = 0; c < CC - 1; ++c) {
        s = fmaf(Pr[c], s, Qr[c]);
        S_ws[((size_t)(b * (CC - 1) + c)) * (Mm * Dd) + md] = s;
    }
}

// ============ scan pass 3: rescan chunk from known start, emit read ============
#define RD_BODY(S, tt) do {                                                  \
    float acc0 = 0.f, acc1 = 0.f;                                            \
    _Pragma("unroll")                                                        \
    for (int m = 0; m < Mm; m += 2) {                                        \
        float wm0 = bcast_lane(w##S, m);                                     \
        float wm1 = bcast_lane(w##S, m + 1);                                 \
        acc0 = fmaf(wm0, mv[m], acc0);                                       \
        mv[m] = fmaf(wm0, fmaf(-e##S, mv[m], a##S), mv[m]);                  \
        acc1 = fmaf(wm1, mv[m + 1], acc1);                                   \
        mv[m + 1] = fmaf(wm1, fmaf(-e##S, mv[m + 1], a##S), mv[m + 1]);      \
    }                                                                        \
    read_ws[(blBase + (tt)) * Dd + d] = acc0 + acc1;                         \
    } while (0)

__global__ void __launch_bounds__(128) kern_scan_rd(
        const float* __restrict__ Mv0,
        const float* __restrict__ S_ws,
        const float* __restrict__ w_ws,
        const float* __restrict__ e_ws,
        const float* __restrict__ a_ws,
        float* __restrict__ read_ws,
        int C, int T) {
    int b = blockIdx.x / C, c = blockIdx.x % C;
    int d = threadIdx.x;
    int lane = d & 63;
    float mv[Mm];
    if (c == 0) {
#pragma unroll
        for (int m = 0; m < Mm; ++m) mv[m] = Mv0[m * Dd + d];
    } else {
        size_t sb = ((size_t)(b * (C - 1) + (c - 1))) * (Mm * Dd) + d;
#pragma unroll
        for (int m = 0; m < Mm; ++m) mv[m] = S_ws[sb + m * Dd];
    }

    size_t blBase = (size_t)b * Ll + (size_t)c * T;
    float w0 = 0.f, e0 = 0.f, a0 = 0.f;
    float w1 = 0.f, e1 = 0.f, a1 = 0.f;
    float w2 = 0.f, e2 = 0.f, a2 = 0.f;
    PQ_LOAD(0, 0);
    PQ_LOAD(1, 1);
    for (int tt = 0; tt < T; tt += 3) {
        PQ_LOAD(2, tt + 2);  RD_BODY(0, tt);
        if (tt + 1 < T) { PQ_LOAD(0, tt + 3);  RD_BODY(1, tt + 1); }
        if (tt + 2 < T) { PQ_LOAD(1, tt + 4);  RD_BODY(2, tt + 2); }
    }
}

// ============ kernel 4: p = sigmoid(tanh([read|k]@fW^T+fb) @ pW^T + pb) ============
// 128 thr = 2 waves, 32 pos/block. Lane (=row 0..127) holds a K-half of its f_W
// row in VGPRs; two stages (read-half, k-half) with per-thread LDS carry (no sync).
// Operand values via scalar loads. Final reduce: wave shuffle + tiny LDS combine.
__global__ void __launch_bounds__(128) kern_out(
        const int* __restrict__ skills,
        const float* __restrict__ read_ws,
        const float* __restrict__ k_emb,
        const float* __restrict__ f_W, const float* __restrict__ f_b,
        const float* __restrict__ p_W, const float* __restrict__ p_b,
        float* __restrict__ out) {
    __shared__ float part[32][Dd];    // [pos][row] private carry, same-thread RW
    __shared__ float pw2[2][32];
    int tid = threadIdx.x, blk = blockIdx.x;
    int wave = tid >> 6, lane = tid & 63;
    int row = tid;                    // 0..127
    const float4* wp = (const float4*)(f_W + (size_t)row * (2 * Dd));
    float4 wreg[32];
#pragma unroll
    for (int j = 0; j < 32; ++j) wreg[j] = wp[j];          // K = 0..127 (read half)

    // ---- stage 0: read-half partial dots ----
    for (int p = 0; p < 32; ++p) {
        int idx = blk * 32 + p;
        int b = idx / (Ll - 1);
        int l = idx - b * (Ll - 1) + 1;
        int bl = b * Ll + l;
        const float4* rp = (const float4*)(read_ws + (size_t)bl * Dd);
        float acc = 0.f;
#pragma unroll
        for (int j = 0; j < 32; ++j) {
            float4 v = rp[j];                  // uniform -> s_load
            acc = fmaf(wreg[j].x, v.x, acc);
            acc = fmaf(wreg[j].y, v.y, acc);
            acc = fmaf(wreg[j].z, v.z, acc);
            acc = fmaf(wreg[j].w, v.w, acc);
        }
        part[p][row] = acc;
    }

#pragma unroll
    for (int j = 0; j < 32; ++j) wreg[j] = wp[32 + j];     // K = 128..255 (k half)
    float fb = f_b[row];
    float pw = p_W[row];

    // ---- stage 1: k-half, activation, head, reduce ----
    for (int p = 0; p < 32; ++p) {
        int idx = blk * 32 + p;
        int b = idx / (Ll - 1);
        int l = idx - b * (Ll - 1) + 1;
        int bl = b * Ll + l;
        int sk = __builtin_amdgcn_readfirstlane(skills[bl]);
        const float4* kp = (const float4*)(k_emb + (size_t)sk * Dd);
        float acc = part[p][row];
#pragma unroll
        for (int j = 0; j < 32; ++j) {
            float4 v = kp[j];                  // uniform -> s_load
            acc = fmaf(wreg[j].x, v.x, acc);
            acc = fmaf(wreg[j].y, v.y, acc);
            acc = fmaf(wreg[j].z, v.z, acc);
            acc = fmaf(wreg[j].w, v.w, acc);
        }
        float val = tanhf(acc + fb) * pw;
        for (int off = 32; off > 0; off >>= 1) val += __shfl_down(val, off);
        if (lane == 0) pw2[wave][p] = val;
    }
    __syncthreads();
    if (tid < 32) {
        float s = pw2[0][tid] + pw2[1][tid] + p_b[0];
        out[blk * 32 + tid] = 1.f / (1.f + expf(-s));
    }
}

extern "C" void kernel_launch(void* const* d_in, const int* in_sizes, int n_in,
                              void* d_out, int out_size, void* d_ws, size_t ws_size,
                              hipStream_t stream) {
    const int*   skills    = (const int*)  d_in[0];
    const int*   responses = (const int*)  d_in[1];
    const float* k_emb     = (const float*)d_in[2];
    const float* v_emb     = (const float*)d_in[3];
    const float* Mk        = (const float*)d_in[4];
    const float* Mv0       = (const float*)d_in[5];
    const float* e_W       = (const float*)d_in[6];
    const float* e_b       = (const float*)d_in[7];
    const float* a_W       = (const float*)d_in[8];
    const float* a_b       = (const float*)d_in[9];
    const float* f_W       = (const float*)d_in[10];
    const float* f_b       = (const float*)d_in[11];
    const float* p_W       = (const float*)d_in[12];
    const float* p_b       = (const float*)d_in[13];
    (void)in_sizes; (void)n_in; (void)out_size;

    float* out = (float*)d_out;

    float* ws      = (float*)d_ws;
    float* w_ws    = ws;                                  // B*L*M
    float* e_ws    = w_ws + (size_t)Bb * Ll * Mm;         // B*L*D
    float* a_ws    = e_ws + (size_t)Bb * Ll * Dd;         // B*L*D
    float* read_ws = a_ws + (size_t)Bb * Ll * Dd;         // B*L*D
    float* extra   = read_ws + (size_t)Bb * Ll * Dd;

    const size_t baseF = (size_t)Bb * Ll * Mm + 3 * (size_t)Bb * Ll * Dd;
    const size_t BMD   = (size_t)Bb * Mm * Dd;
    int C = 1;
    const int cands[3] = {8, 5, 2};
    for (int i = 0; i < 3; ++i) {
        size_t need = (baseF + BMD * (3 * (size_t)cands[i] - 1)) * sizeof(float);
        if (ws_size >= need) { C = cands[i]; break; }
    }
    int T = Ll / C;
    float* P_ws = extra;
    float* Q_ws = P_ws + BMD * C;
    float* S_ws = Q_ws + BMD * C;

    kern_w  <<<Bb * Ll / 32, 256, 0, stream>>>(skills, k_emb, Mk, w_ws);
    kern_ea <<<Bb * Ll / 32, 256, 0, stream>>>(skills, responses, v_emb,
                                               e_W, e_b, a_W, a_b, e_ws, a_ws);
    if (C > 1) {
        kern_scan_pq<<<Bb * C, 128, 0, stream>>>(w_ws, e_ws, a_ws, P_ws, Q_ws, C, T);
        int cgrid = (int)(BMD / 256);
        if      (C == 8) kern_scan_comb_t<8><<<cgrid, 256, 0, stream>>>(Mv0, P_ws, Q_ws, S_ws);
        else if (C == 5) kern_scan_comb_t<5><<<cgrid, 256, 0, stream>>>(Mv0, P_ws, Q_ws, S_ws);
        else             kern_scan_comb_t<2><<<cgrid, 256, 0, stream>>>(Mv0, P_ws, Q_ws, S_ws);
    }
    kern_scan_rd<<<Bb * C, 128, 0, stream>>>(Mv0, S_ws, w_ws, e_ws, a_ws, read_ws, C, T);
    kern_out<<<Bb * (Ll - 1) / 32, 128, 0, stream>>>(skills, read_ws, k_emb,
                                                     f_W, f_b, p_W, p_b, out);
}

// Round 8
// 193.780 us; speedup vs baseline: 1.5583x; 1.5583x over previous
//
#include <hip/hip_runtime.h>
#include <hip/hip_bf16.h>

#define Bb 64
#define Ll 200
#define NSs 1000
#define Dd 128
#define Mm 50

__device__ __forceinline__ float bcast_lane(float v, int l) {
    return __int_as_float(__builtin_amdgcn_readlane(__float_as_int(v), l));
}

// ============ kernel 1: w = softmax(k @ Mk^T) over M=50 ============
// 16 pos/block (4 waves x 4 pos), Mk staged once, float4 LDS reads. (R5 version)
__global__ void __launch_bounds__(256) kern_w(
        const int* __restrict__ skills,
        const float* __restrict__ k_emb,
        const float* __restrict__ Mk,
        float* __restrict__ w_out) {
    __shared__ float mk[Mm][Dd + 4];
    __shared__ float kr[16][Dd + 4];
    int tid = threadIdx.x;
    int blk = blockIdx.x;

    for (int lin = tid; lin < (Mm * Dd) / 4; lin += 256) {   // 1600 float4
        float4 f = ((const float4*)Mk)[lin];
        int m = lin >> 5;
        int c4 = lin & 31;
        *(float4*)&mk[m][c4 * 4] = f;
    }
    for (int lin = tid; lin < 16 * 32; lin += 256) {          // 512 float4
        int r  = lin >> 5;
        int c4 = lin & 31;
        int bl = blk * 16 + r;
        float4 f = ((const float4*)(k_emb + (size_t)skills[bl] * Dd))[c4];
        *(float4*)&kr[r][c4 * 4] = f;
    }
    __syncthreads();

    int wave = tid >> 6;
    int lane = tid & 63;
    int mm   = (lane < Mm) ? lane : 0;
    float acc[4] = {0.f, 0.f, 0.f, 0.f};
#pragma unroll 2
    for (int q = 0; q < 32; ++q) {
        float4 mkv = *(const float4*)&mk[mm][q * 4];
#pragma unroll
        for (int i = 0; i < 4; ++i) {
            float4 kv = *(const float4*)&kr[wave * 4 + i][q * 4];
            acc[i] = fmaf(mkv.x, kv.x, acc[i]);
            acc[i] = fmaf(mkv.y, kv.y, acc[i]);
            acc[i] = fmaf(mkv.z, kv.z, acc[i]);
            acc[i] = fmaf(mkv.w, kv.w, acc[i]);
        }
    }
#pragma unroll
    for (int i = 0; i < 4; ++i) {
        float logit = (lane < Mm) ? acc[i] : -1e30f;
        float mx = logit;
        for (int off = 32; off > 0; off >>= 1) mx = fmaxf(mx, __shfl_down(mx, off));
        mx = __shfl(mx, 0);
        float ex = (lane < Mm) ? expf(logit - mx) : 0.f;
        float sm = ex;
        for (int off = 32; off > 0; off >>= 1) sm += __shfl_down(sm, off);
        sm = __shfl(sm, 0);
        int bl = blk * 16 + wave * 4 + i;
        if (lane < Mm) w_out[(size_t)bl * Mm + lane] = ex / sm;
    }
}

// ============ kernel 2: e = sigmoid(V@eW^T+eb), a = tanh(V@aW^T+ab) ============
// 32 pos/block, 256 thr = 4 waves. Wave w owns concat rows [w*64, w*64+64) in
// 4 sub-chunks of 16 (wave-private tile, no inner barriers). Lane tile:
// positions {pg+8i}, rows {og+8j} -> all b128 LDS reads conflict-free.
__global__ void __launch_bounds__(256) kern_ea(
        const int* __restrict__ skills,
        const int* __restrict__ responses,
        const float* __restrict__ v_emb,
        const float* __restrict__ e_W, const float* __restrict__ e_b,
        const float* __restrict__ a_W, const float* __restrict__ a_b,
        float* __restrict__ e_out, float* __restrict__ a_out) {
    __shared__ float vt[32][Dd + 4];          // 16.9 KB
    __shared__ float wt[4][16][Dd + 4];       // 33.8 KB (wave-private 16-row slices)
    int tid = threadIdx.x;
    int blk = blockIdx.x;

#pragma unroll
    for (int i = 0; i < 4; ++i) {
        int lin = i * 256 + tid;
        int r   = lin >> 5;
        int c4  = lin & 31;
        int bl  = blk * 32 + r;
        int rr  = responses[bl];
        int x   = skills[bl] + NSs * ((rr > -1) ? rr : 0);
        float4 f = ((const float4*)(v_emb + (size_t)x * Dd))[c4];
        *(float4*)&vt[r][c4 * 4] = f;
    }
    __syncthreads();

    int wave = tid >> 6, lane = tid & 63;
    int pg = lane >> 3, og = lane & 7;

    for (int s = 0; s < 4; ++s) {
        int base_row = wave * 64 + s * 16;            // concat space [0,256)
        bool is_e    = base_row < 128;
        const float* W = is_e ? e_W : a_W;
        int wrow0 = is_e ? base_row : base_row - 128;

        // wave stages its 16 weight rows (512 float4 by 64 lanes)
#pragma unroll
        for (int i = 0; i < 8; ++i) {
            int lin = i * 64 + lane;
            int r   = lin >> 5;
            int c4  = lin & 31;
            float4 f = ((const float4*)(W + (size_t)(wrow0 + r) * Dd))[c4];
            *(float4*)&wt[wave][r][c4 * 4] = f;
        }
        // wave-private tile: per-wave LDS ordering makes a barrier unnecessary

        float acc[4][2] = {};
#pragma unroll 2
        for (int q = 0; q < 32; ++q) {
            float4 av[4], bv[2];
#pragma unroll
            for (int i = 0; i < 4; ++i) av[i] = *(const float4*)&vt[pg + 8 * i][q * 4];
#pragma unroll
            for (int j = 0; j < 2; ++j) bv[j] = *(const float4*)&wt[wave][og + 8 * j][q * 4];
#pragma unroll
            for (int i = 0; i < 4; ++i)
#pragma unroll
                for (int j = 0; j < 2; ++j) {
                    acc[i][j] = fmaf(av[i].x, bv[j].x, acc[i][j]);
                    acc[i][j] = fmaf(av[i].y, bv[j].y, acc[i][j]);
                    acc[i][j] = fmaf(av[i].z, bv[j].z, acc[i][j]);
                    acc[i][j] = fmaf(av[i].w, bv[j].w, acc[i][j]);
                }
        }

        float* dst = is_e ? e_out : a_out;
#pragma unroll
        for (int j = 0; j < 2; ++j) {
            int row = wrow0 + og + 8 * j;
            float bias = (is_e ? e_b : a_b)[row];
#pragma unroll
            for (int i = 0; i < 4; ++i) {
                int bl = blk * 32 + pg + 8 * i;
                float v = acc[i][j] + bias;
                dst[(size_t)bl * Dd + row] = is_e ? (1.f / (1.f + expf(-v))) : tanhf(v);
            }
        }
    }
}

// ============ scan pass 1: per-chunk affine transfer (P, Q) ============
#define PQ_LOAD(S, tt) do { int _t = (tt);                                   \
    if (_t < T) { size_t _bl = blBase + _t;                                  \
        w##S = (lane < Mm) ? w_ws[_bl * Mm + lane] : 0.f;                    \
        e##S = e_ws[_bl * Dd + d];  a##S = a_ws[_bl * Dd + d]; } } while (0)

#define PQ_BODY(S) do {                                                      \
    _Pragma("unroll")                                                        \
    for (int m = 0; m < Mm; ++m) {                                           \
        float wm = bcast_lane(w##S, m);                                      \
        float A  = fmaf(-wm, e##S, 1.f);                                     \
        Q[m] = fmaf(A, Q[m], wm * a##S);                                     \
        P[m] *= A; } } while (0)

__global__ void __launch_bounds__(128) kern_scan_pq(
        const float* __restrict__ w_ws,
        const float* __restrict__ e_ws,
        const float* __restrict__ a_ws,
        float* __restrict__ P_ws, float* __restrict__ Q_ws,
        int C, int T) {
    int b = blockIdx.x / C, c = blockIdx.x % C;
    int d = threadIdx.x;
    int lane = d & 63;
    float P[Mm], Q[Mm];
#pragma unroll
    for (int m = 0; m < Mm; ++m) { P[m] = 1.f; Q[m] = 0.f; }

    size_t blBase = (size_t)b * Ll + (size_t)c * T;
    float w0 = 0.f, e0 = 0.f, a0 = 0.f;
    float w1 = 0.f, e1 = 0.f, a1 = 0.f;
    float w2 = 0.f, e2 = 0.f, a2 = 0.f;
    PQ_LOAD(0, 0);
    PQ_LOAD(1, 1);
    for (int tt = 0; tt < T; tt += 3) {
        PQ_LOAD(2, tt + 2);  PQ_BODY(0);
        if (tt + 1 < T) { PQ_LOAD(0, tt + 3);  PQ_BODY(1); }
        if (tt + 2 < T) { PQ_LOAD(1, tt + 4);  PQ_BODY(2); }
    }
    size_t base = ((size_t)(b * C + c)) * (Mm * Dd) + d;
#pragma unroll
    for (int m = 0; m < Mm; ++m) {
        P_ws[base + m * Dd] = P[m];
        Q_ws[base + m * Dd] = Q[m];
    }
}

// ============ scan pass 2: chunk-boundary combine (compile-time C) ============
template <int CC>
__global__ void kern_scan_comb_t(
        const float* __restrict__ Mv0,
        const float* __restrict__ P_ws, const float* __restrict__ Q_ws,
        float* __restrict__ S_ws) {
    int idx = blockIdx.x * 256 + threadIdx.x;
    int b   = idx / (Mm * Dd);
    int md  = idx % (Mm * Dd);
    float Pr[CC - 1], Qr[CC - 1];
#pragma unroll
    for (int c = 0; c < CC - 1; ++c) {
        size_t pq = ((size_t)(b * CC + c)) * (Mm * Dd) + md;
        Pr[c] = P_ws[pq];
        Qr[c] = Q_ws[pq];
    }
    float s = Mv0[md];
#pragma unroll
    for (int c = 0; c < CC - 1; ++c) {
        s = fmaf(Pr[c], s, Qr[c]);
        S_ws[((size_t)(b * (CC - 1) + c)) * (Mm * Dd) + md] = s;
    }
}

// ============ scan pass 3: rescan chunk from known start, emit read ============
#define RD_BODY(S, tt) do {                                                  \
    float acc0 = 0.f, acc1 = 0.f;                                            \
    _Pragma("unroll")                                                        \
    for (int m = 0; m < Mm; m += 2) {                                        \
        float wm0 = bcast_lane(w##S, m);                                     \
        float wm1 = bcast_lane(w##S, m + 1);                                 \
        acc0 = fmaf(wm0, mv[m], acc0);                                       \
        mv[m] = fmaf(wm0, fmaf(-e##S, mv[m], a##S), mv[m]);                  \
        acc1 = fmaf(wm1, mv[m + 1], acc1);                                   \
        mv[m + 1] = fmaf(wm1, fmaf(-e##S, mv[m + 1], a##S), mv[m + 1]);      \
    }                                                                        \
    read_ws[(blBase + (tt)) * Dd + d] = acc0 + acc1;                         \
    } while (0)

__global__ void __launch_bounds__(128) kern_scan_rd(
        const float* __restrict__ Mv0,
        const float* __restrict__ S_ws,
        const float* __restrict__ w_ws,
        const float* __restrict__ e_ws,
        const float* __restrict__ a_ws,
        float* __restrict__ read_ws,
        int C, int T) {
    int b = blockIdx.x / C, c = blockIdx.x % C;
    int d = threadIdx.x;
    int lane = d & 63;
    float mv[Mm];
    if (c == 0) {
#pragma unroll
        for (int m = 0; m < Mm; ++m) mv[m] = Mv0[m * Dd + d];
    } else {
        size_t sb = ((size_t)(b * (C - 1) + (c - 1))) * (Mm * Dd) + d;
#pragma unroll
        for (int m = 0; m < Mm; ++m) mv[m] = S_ws[sb + m * Dd];
    }

    size_t blBase = (size_t)b * Ll + (size_t)c * T;
    float w0 = 0.f, e0 = 0.f, a0 = 0.f;
    float w1 = 0.f, e1 = 0.f, a1 = 0.f;
    float w2 = 0.f, e2 = 0.f, a2 = 0.f;
    PQ_LOAD(0, 0);
    PQ_LOAD(1, 1);
    for (int tt = 0; tt < T; tt += 3) {
        PQ_LOAD(2, tt + 2);  RD_BODY(0, tt);
        if (tt + 1 < T) { PQ_LOAD(0, tt + 3);  RD_BODY(1, tt + 1); }
        if (tt + 2 < T) { PQ_LOAD(1, tt + 4);  RD_BODY(2, tt + 2); }
    }
}

// ============ kernel 4: p = sigmoid(tanh([read|k]@fW^T+fb) @ pW^T + pb) ============
// 32 pos/block, 256 thr = 4 waves. Wave w owns f_W rows [w*32,+32) in 2 subs of
// 16 (K accumulated over both halves per sub). Lane tile: positions {pg+8i},
// rows {og+8j} -> conflict-free b128 reads. wt wave-private, no inner barriers.
__global__ void __launch_bounds__(256) kern_out(
        const int* __restrict__ skills,
        const float* __restrict__ read_ws,
        const float* __restrict__ k_emb,
        const float* __restrict__ f_W, const float* __restrict__ f_b,
        const float* __restrict__ p_W, const float* __restrict__ p_b,
        float* __restrict__ out) {
    __shared__ float ct[32][2 * Dd + 4];       // 33.3 KB, stride 260 (65 quads, odd)
    __shared__ float wt[4][16][Dd + 4];        // 33.8 KB
    __shared__ float pf[32][8];
    int tid = threadIdx.x;
    int blk = blockIdx.x;

    // stage 32 rows of [read|k]: 2048 float4
#pragma unroll
    for (int i = 0; i < 8; ++i) {
        int lin = i * 256 + tid;
        int r   = lin >> 6;
        int c4  = lin & 63;
        int idx = blk * 32 + r;
        int b   = idx / (Ll - 1);
        int l   = idx % (Ll - 1) + 1;
        int bl  = b * Ll + l;
        float4 f;
        if (c4 < 32) f = ((const float4*)(read_ws + (size_t)bl * Dd))[c4];
        else         f = ((const float4*)(k_emb + (size_t)skills[bl] * Dd))[c4 - 32];
        *(float4*)&ct[r][c4 * 4] = f;
    }
    ((float*)pf)[tid] = 0.f;
    __syncthreads();

    int wave = tid >> 6, lane = tid & 63;
    int pg = lane >> 3, og = lane & 7;

    float ppart[4] = {0.f, 0.f, 0.f, 0.f};
    for (int sub = 0; sub < 2; ++sub) {
        float acc[4][2] = {};
        for (int h = 0; h < 2; ++h) {
            // wave stages 16 f_W rows, K cols [h*128,+128) (512 float4)
#pragma unroll
            for (int i = 0; i < 8; ++i) {
                int lin = i * 64 + lane;
                int r   = lin >> 5;
                int c4  = lin & 31;
                float4 f = ((const float4*)(f_W +
                            (size_t)(wave * 32 + sub * 16 + r) * (2 * Dd)))[h * 32 + c4];
                *(float4*)&wt[wave][r][c4 * 4] = f;
            }
            // wave-private tile: no barrier
#pragma unroll 2
            for (int q = 0; q < 32; ++q) {
                int k = h * 128 + q * 4;
                float4 av[4], bv[2];
#pragma unroll
                for (int i = 0; i < 4; ++i) av[i] = *(const float4*)&ct[pg + 8 * i][k];
#pragma unroll
                for (int j = 0; j < 2; ++j) bv[j] = *(const float4*)&wt[wave][og + 8 * j][q * 4];
#pragma unroll
                for (int i = 0; i < 4; ++i)
#pragma unroll
                    for (int j = 0; j < 2; ++j) {
                        acc[i][j] = fmaf(av[i].x, bv[j].x, acc[i][j]);
                        acc[i][j] = fmaf(av[i].y, bv[j].y, acc[i][j]);
                        acc[i][j] = fmaf(av[i].z, bv[j].z, acc[i][j]);
                        acc[i][j] = fmaf(av[i].w, bv[j].w, acc[i][j]);
                    }
            }
        }
        // finalize this sub's rows: tanh + p-head partial
#pragma unroll
        for (int j = 0; j < 2; ++j) {
            int row = wave * 32 + sub * 16 + og + 8 * j;
            float fb = f_b[row];
            float pw = p_W[row];
#pragma unroll
            for (int i = 0; i < 4; ++i)
                ppart[i] = fmaf(tanhf(acc[i][j] + fb), pw, ppart[i]);
        }
    }
    // reduce over og (width-8 shuffle), then across waves via pf
#pragma unroll
    for (int i = 0; i < 4; ++i) {
        float v = ppart[i];
        for (int off = 4; off > 0; off >>= 1) v += __shfl_down(v, off, 8);
        if (og == 0) pf[pg + 8 * i][wave] = v;
    }
    __syncthreads();
    if (tid < 32) {
        float s = pf[tid][0] + pf[tid][1] + pf[tid][2] + pf[tid][3] + p_b[0];
        out[blk * 32 + tid] = 1.f / (1.f + expf(-s));
    }
}

extern "C" void kernel_launch(void* const* d_in, const int* in_sizes, int n_in,
                              void* d_out, int out_size, void* d_ws, size_t ws_size,
                              hipStream_t stream) {
    const int*   skills    = (const int*)  d_in[0];
    const int*   responses = (const int*)  d_in[1];
    const float* k_emb     = (const float*)d_in[2];
    const float* v_emb     = (const float*)d_in[3];
    const float* Mk        = (const float*)d_in[4];
    const float* Mv0       = (const float*)d_in[5];
    const float* e_W       = (const float*)d_in[6];
    const float* e_b       = (const float*)d_in[7];
    const float* a_W       = (const float*)d_in[8];
    const float* a_b       = (const float*)d_in[9];
    const float* f_W       = (const float*)d_in[10];
    const float* f_b       = (const float*)d_in[11];
    const float* p_W       = (const float*)d_in[12];
    const float* p_b       = (const float*)d_in[13];
    (void)in_sizes; (void)n_in; (void)out_size;

    float* out = (float*)d_out;

    float* ws      = (float*)d_ws;
    float* w_ws    = ws;                                  // B*L*M
    float* e_ws    = w_ws + (size_t)Bb * Ll * Mm;         // B*L*D
    float* a_ws    = e_ws + (size_t)Bb * Ll * Dd;         // B*L*D
    float* read_ws = a_ws + (size_t)Bb * Ll * Dd;         // B*L*D
    float* extra   = read_ws + (size_t)Bb * Ll * Dd;

    const size_t baseF = (size_t)Bb * Ll * Mm + 3 * (size_t)Bb * Ll * Dd;
    const size_t BMD   = (size_t)Bb * Mm * Dd;
    int C = 1;
    const int cands[3] = {8, 5, 2};
    for (int i = 0; i < 3; ++i) {
        size_t need = (baseF + BMD * (3 * (size_t)cands[i] - 1)) * sizeof(float);
        if (ws_size >= need) { C = cands[i]; break; }
    }
    int T = Ll / C;
    float* P_ws = extra;
    float* Q_ws = P_ws + BMD * C;
    float* S_ws = Q_ws + BMD * C;

    kern_w  <<<Bb * Ll / 16, 256, 0, stream>>>(skills, k_emb, Mk, w_ws);
    kern_ea <<<Bb * Ll / 32, 256, 0, stream>>>(skills, responses, v_emb,
                                               e_W, e_b, a_W, a_b, e_ws, a_ws);
    if (C > 1) {
        kern_scan_pq<<<Bb * C, 128, 0, stream>>>(w_ws, e_ws, a_ws, P_ws, Q_ws, C, T);
        int cgrid = (int)(BMD / 256);
        if      (C == 8) kern_scan_comb_t<8><<<cgrid, 256, 0, stream>>>(Mv0, P_ws, Q_ws, S_ws);
        else if (C == 5) kern_scan_comb_t<5><<<cgrid, 256, 0, stream>>>(Mv0, P_ws, Q_ws, S_ws);
        else             kern_scan_comb_t<2><<<cgrid, 256, 0, stream>>>(Mv0, P_ws, Q_ws, S_ws);
    }
    kern_scan_rd<<<Bb * C, 128, 0, stream>>>(Mv0, S_ws, w_ws, e_ws, a_ws, read_ws, C, T);
    kern_out<<<Bb * (Ll - 1) / 32, 256, 0, stream>>>(skills, read_ws, k_emb,
                                                     f_W, f_b, p_W, p_b, out);
}